// Round 2
// baseline (612.106 us; speedup 1.0000x reference)
//
#include <hip/hip_runtime.h>
#include <stdint.h>

#define B_ 4
#define T_ 2048
#define C_ 1024
#define H_ 16
#define HD_ 64

typedef __attribute__((ext_vector_type(8))) short short8;
typedef __attribute__((ext_vector_type(4))) float f32x4;

typedef uint32_t __attribute__((address_space(3))) lds_u32;
typedef const uint32_t __attribute__((address_space(1))) glb_u32;

__device__ inline void async16(const void* g, void* l) {
    __builtin_amdgcn_global_load_lds((glb_u32*)g, (lds_u32*)l, 16, 0, 0);
}

__device__ inline short f2bf(float f) {
    union { float f; uint32_t u; } x; x.f = f;
    uint32_t r = (x.u + 0x7fffu + ((x.u >> 16) & 1u)) >> 16;
    return (short)r;
}
__device__ inline float bf2f(short b) {
    union { uint32_t u; float f; } x; x.u = ((uint32_t)(uint16_t)b) << 16;
    return x.f;
}

// Decide on-device whether inputs are fp32 or bf16.
// If bf16: low 16 bits of each u32 are a bf16 ~N(0,1) -> |v| in (1e-5,1e5) ~always.
// If fp32: low 16 bits are mantissa bits (~uniform) -> sane only ~13% of the time.
__global__ void detect_f32(const uint32_t* __restrict__ x, int* __restrict__ flag) {
    __shared__ int cnt;
    if (threadIdx.x == 0) cnt = 0;
    __syncthreads();
    int sane = 0;
    for (int i = threadIdx.x; i < 1024; i += 256) {
        float v = bf2f((short)(x[i] & 0xFFFFu));
        float a = fabsf(v);
        if (a > 1e-5f && a < 1e5f) sane++;
    }
    atomicAdd(&cnt, sane);
    __syncthreads();
    if (threadIdx.x == 0) *flag = (cnt < 512) ? 1 : 0;
}

// Canonicalize to bf16: convert (fp32 source) or copy (bf16 source). n % 8 == 0.
__global__ void to_bf16(const void* __restrict__ src, short* __restrict__ dst,
                        int n, const int* __restrict__ flag) {
    const int i = (blockIdx.x * blockDim.x + threadIdx.x) * 8;
    if (i >= n) return;
    if (*flag) {
        const float* s = (const float*)src;
        short8 o;
#pragma unroll
        for (int j = 0; j < 8; j++) o[j] = f2bf(s[i + j]);
        *(short8*)&dst[i] = o;
    } else {
        *(short8*)&dst[i] = *(const short8*)((const short*)src + i);
    }
}

// C = A @ B^T (+bias), A[M,K], B[N,K] row-major bf16.
// DUAL: output dtype chosen at runtime by *flag (fp32 vs bf16); else bf16.
template <bool DUAL>
__global__ __launch_bounds__(256) void gemm_bt(
    const short* __restrict__ A, const short* __restrict__ Bm,
    const short* __restrict__ bias_bf, void* __restrict__ Cout,
    int M, int N, int K, const int* __restrict__ flag)
{
    __shared__ short As[128 * 32];
    __shared__ short Bs[128 * 32];
    const int tid  = threadIdx.x;
    const int lane = tid & 63;
    const int wave = tid >> 6;
    const int quad = lane >> 4;
    const int lcol = lane & 15;
    const int m0 = blockIdx.y * 128;
    const int n0 = blockIdx.x * 128;
    const int wm = (wave >> 1) * 64;
    const int wn = (wave & 1) * 64;
    const int isf32 = DUAL ? *flag : 0;

    f32x4 acc[4][4];
#pragma unroll
    for (int i = 0; i < 4; i++)
#pragma unroll
        for (int j = 0; j < 4; j++) acc[i][j] = f32x4{0.f, 0.f, 0.f, 0.f};

    const int idx0 = tid * 8;            // element index in 128x32 tile
    const int row0 = idx0 >> 5, col0 = idx0 & 31;
    const int idx1 = (256 + tid) * 8;
    const int row1 = idx1 >> 5, col1 = idx1 & 31;

    for (int k0 = 0; k0 < K; k0 += 32) {
        async16(&A[(size_t)(m0 + row0) * K + k0 + col0], &As[idx0]);
        async16(&A[(size_t)(m0 + row1) * K + k0 + col1], &As[idx1]);
        async16(&Bm[(size_t)(n0 + row0) * K + k0 + col0], &Bs[idx0]);
        async16(&Bm[(size_t)(n0 + row1) * K + k0 + col1], &Bs[idx1]);
        __syncthreads();

        short8 af[4], bfr[4];
#pragma unroll
        for (int mi = 0; mi < 4; mi++)
            af[mi] = *(const short8*)&As[(wm + mi * 16 + lcol) * 32 + quad * 8];
#pragma unroll
        for (int ni = 0; ni < 4; ni++)
            bfr[ni] = *(const short8*)&Bs[(wn + ni * 16 + lcol) * 32 + quad * 8];
#pragma unroll
        for (int mi = 0; mi < 4; mi++)
#pragma unroll
            for (int ni = 0; ni < 4; ni++)
                acc[mi][ni] = __builtin_amdgcn_mfma_f32_16x16x32_bf16(
                    af[mi], bfr[ni], acc[mi][ni], 0, 0, 0);
        __syncthreads();
    }

#pragma unroll
    for (int ni = 0; ni < 4; ni++) {
        const int col = n0 + wn + ni * 16 + lcol;
        const float bv = bias_bf ? bf2f(bias_bf[col]) : 0.f;
#pragma unroll
        for (int mi = 0; mi < 4; mi++) {
            const int row = m0 + wm + mi * 16 + quad * 4;
#pragma unroll
            for (int r = 0; r < 4; r++) {
                const float val = acc[mi][ni][r] + bv;
                const size_t off = (size_t)(row + r) * N + col;
                if (DUAL && isf32) ((float*)Cout)[off] = val;
                else               ((short*)Cout)[off] = f2bf(val);
            }
        }
    }
}

// Flash attention: one block = 64 Q rows of one (b,h); 4 waves x 16 Q rows.
// qkv layout per reference: col = h*192 + {0:q, 64:k, 128:v} + d.
__global__ __launch_bounds__(256) void attn(const short* __restrict__ qkv,
                                            short* __restrict__ att)
{
    __shared__ short lds_k[32][72];      // [key][d], pad 64->72
    __shared__ short lds_vt[64][40];     // [d][key], pad 32->40
    __shared__ short lds_p[4][16][40];   // per-wave P [q][key], pad 32->40

    const int tid  = threadIdx.x;
    const int lane = tid & 63;
    const int wave = tid >> 6;
    const int quad = lane >> 4;
    const int lcol = lane & 15;

    const int qblk = blockIdx.x & 31;    // T/64 = 32
    const int bh   = blockIdx.x >> 5;
    const int b    = bh >> 4;            // H = 16
    const int h    = bh & 15;
    const int q0   = qblk * 64;
    const int qw0  = q0 + wave * 16;

    const size_t rowstride = 3 * C_;     // 3072
    const size_t bhbase = (size_t)b * T_ * rowstride + (size_t)h * (3 * HD_);

    // Q fragments (A-operand: m=lcol, k=quad*8+j, two d-halves)
    short8 qf0, qf1;
    {
        const size_t base = bhbase + (size_t)(qw0 + lcol) * rowstride + quad * 8;
        qf0 = *(const short8*)&qkv[base];
        qf1 = *(const short8*)&qkv[base + 32];
    }

    const float NEG = -1e30f;            // finite sentinel: no inf-inf NaN possible
    f32x4 o[4];
#pragma unroll
    for (int i = 0; i < 4; i++) o[i] = f32x4{0.f, 0.f, 0.f, 0.f};
    float m_i[4], l_i[4];
#pragma unroll
    for (int r = 0; r < 4; r++) { m_i[r] = NEG; l_i[r] = 0.f; }

    const int skey = tid >> 3;           // 0..31
    const int sd0  = (tid & 7) * 8;      // 0..56

    const int ntiles = q0 / 32 + 2;
    for (int kt = 0; kt < ntiles; ++kt) {
        const int k0 = kt * 32;
        __syncthreads();
        {   // stage K [32][64] and V transposed [64][32]
            const size_t gb = bhbase + (size_t)(k0 + skey) * rowstride + HD_ + sd0;
            const short8 kv = *(const short8*)&qkv[gb];
            *(short8*)&lds_k[skey][sd0] = kv;
            const short8 vv = *(const short8*)&qkv[gb + HD_];
#pragma unroll
            for (int j = 0; j < 8; j++) lds_vt[sd0 + j][skey] = vv[j];
        }
        __syncthreads();

        // S = Q K^T : keys k0+lcol (S0) and k0+16+lcol (S1)
        const short8 kf00 = *(const short8*)&lds_k[lcol][quad * 8];
        const short8 kf01 = *(const short8*)&lds_k[lcol][32 + quad * 8];
        const short8 kf10 = *(const short8*)&lds_k[16 + lcol][quad * 8];
        const short8 kf11 = *(const short8*)&lds_k[16 + lcol][32 + quad * 8];
        f32x4 S0 = f32x4{0.f, 0.f, 0.f, 0.f};
        f32x4 S1 = f32x4{0.f, 0.f, 0.f, 0.f};
        S0 = __builtin_amdgcn_mfma_f32_16x16x32_bf16(qf0, kf00, S0, 0, 0, 0);
        S0 = __builtin_amdgcn_mfma_f32_16x16x32_bf16(qf1, kf01, S0, 0, 0, 0);
        S1 = __builtin_amdgcn_mfma_f32_16x16x32_bf16(qf0, kf10, S1, 0, 0, 0);
        S1 = __builtin_amdgcn_mfma_f32_16x16x32_bf16(qf1, kf11, S1, 0, 0, 0);

        // online softmax per owned row (row quad*4+r, key col lcol within quad-group)
#pragma unroll
        for (int r = 0; r < 4; r++) {
            const int qrow = qw0 + quad * 4 + r;
            float s0 = (k0 + lcol      <= qrow) ? S0[r] * 0.125f : NEG;
            float s1 = (k0 + 16 + lcol <= qrow) ? S1[r] * 0.125f : NEG;
            float mx = fmaxf(s0, s1);
#pragma unroll
            for (int off = 1; off < 16; off <<= 1) mx = fmaxf(mx, __shfl_xor(mx, off));
            const float mnew  = fmaxf(m_i[r], mx);
            const float alpha = __expf(m_i[r] - mnew);
            const float p0 = __expf(s0 - mnew);
            const float p1 = __expf(s1 - mnew);
            float rs = p0 + p1;
#pragma unroll
            for (int off = 1; off < 16; off <<= 1) rs += __shfl_xor(rs, off);
            l_i[r] = l_i[r] * alpha + rs;
            m_i[r] = mnew;
#pragma unroll
            for (int dt = 0; dt < 4; dt++) o[dt][r] *= alpha;
            lds_p[wave][quad * 4 + r][lcol]      = f2bf(p0);
            lds_p[wave][quad * 4 + r][16 + lcol] = f2bf(p1);
        }

        // O += P V  (P: A-operand from per-wave LDS; V: B-operand from lds_vt)
        const short8 pf = *(const short8*)&lds_p[wave][lcol][quad * 8];
#pragma unroll
        for (int dt = 0; dt < 4; dt++) {
            const short8 vf = *(const short8*)&lds_vt[dt * 16 + lcol][quad * 8];
            o[dt] = __builtin_amdgcn_mfma_f32_16x16x32_bf16(pf, vf, o[dt], 0, 0, 0);
        }
    }

    // normalize + store: att[b, q, h*64 + d]
#pragma unroll
    for (int r = 0; r < 4; r++) {
        const float inv = (l_i[r] > 0.f) ? 1.f / l_i[r] : 0.f;
        const int qrow = qw0 + quad * 4 + r;
#pragma unroll
        for (int dt = 0; dt < 4; dt++) {
            const int col = h * HD_ + dt * 16 + lcol;
            att[(size_t)(b * T_ + qrow) * C_ + col] = f2bf(o[dt][r] * inv);
        }
    }
}

extern "C" void kernel_launch(void* const* d_in, const int* in_sizes, int n_in,
                              void* d_out, int out_size, void* d_ws, size_t ws_size,
                              hipStream_t stream) {
    const int n_x  = B_ * T_ * C_;        // 8388608
    const int n_wq = 3 * C_ * C_;         // 3145728
    const int n_wp = C_ * C_;             // 1048576

    char* ws = (char*)d_ws;
    short* qkv     = (short*)(ws);                               // 50331648 B
    short* x_or_at = (short*)(ws + 50331648);                    // 16777216 B (x_bf, then att)
    short* wq_bf   = (short*)(ws + 50331648 + 16777216);         //  6291456 B
    short* wp_bf   = (short*)(ws + 50331648 + 16777216 + 6291456);           // 2097152 B
    short* bias_bf = (short*)(ws + 50331648 + 16777216 + 6291456 + 2097152); //    2048 B
    int*   flag    = (int*)  (ws + 50331648 + 16777216 + 6291456 + 2097152 + 2048);

    dim3 blk(256);

    detect_f32<<<1, blk, 0, stream>>>((const uint32_t*)d_in[0], flag);

    to_bf16<<<dim3((n_x  / 8 + 255) / 256), blk, 0, stream>>>(d_in[0], x_or_at, n_x,  flag);
    to_bf16<<<dim3((n_wq / 8 + 255) / 256), blk, 0, stream>>>(d_in[1], wq_bf,   n_wq, flag);
    to_bf16<<<dim3((n_wp / 8 + 255) / 256), blk, 0, stream>>>(d_in[2], wp_bf,   n_wp, flag);
    to_bf16<<<dim3(1), blk, 0, stream>>>(d_in[3], bias_bf, C_, flag);

    // qkv = x @ W_qkv^T   [8192,3072]
    gemm_bt<false><<<dim3((3 * C_) / 128, (B_ * T_) / 128), blk, 0, stream>>>(
        x_or_at, wq_bf, nullptr, qkv, B_ * T_, 3 * C_, C_, flag);

    // attention -> att (reuses x_bf region; x no longer needed)
    attn<<<dim3(B_ * H_ * (T_ / 64)), blk, 0, stream>>>(qkv, x_or_at);

    // out = att @ W_proj^T + b_proj  (output dtype per flag)
    gemm_bt<true><<<dim3(C_ / 128, (B_ * T_) / 128), blk, 0, stream>>>(
        x_or_at, wp_bf, bias_bf, d_out, B_ * T_, C_, C_, flag);
}

// Round 3
// 440.417 us; speedup vs baseline: 1.3898x; 1.3898x over previous
//
#include <hip/hip_runtime.h>
#include <stdint.h>

#define B_ 4
#define T_ 2048
#define C_ 1024
#define H_ 16
#define HD_ 64

typedef __attribute__((ext_vector_type(8))) short short8;
typedef __attribute__((ext_vector_type(4))) float f32x4;

typedef uint32_t __attribute__((address_space(3))) lds_u32;
typedef const uint32_t __attribute__((address_space(1))) glb_u32;

__device__ inline void async16(const void* g, void* l) {
    __builtin_amdgcn_global_load_lds((glb_u32*)g, (lds_u32*)l, 16, 0, 0);
}

__device__ inline short f2bf(float f) {
    union { float f; uint32_t u; } x; x.f = f;
    uint32_t r = (x.u + 0x7fffu + ((x.u >> 16) & 1u)) >> 16;
    return (short)r;
}
__device__ inline float bf2f(short b) {
    union { uint32_t u; float f; } x; x.u = ((uint32_t)(uint16_t)b) << 16;
    return x.f;
}

// Decide on-device whether inputs are fp32 or bf16 (see round-1 notes).
__global__ void detect_f32(const uint32_t* __restrict__ x, int* __restrict__ flag) {
    __shared__ int cnt;
    if (threadIdx.x == 0) cnt = 0;
    __syncthreads();
    int sane = 0;
    for (int i = threadIdx.x; i < 1024; i += 256) {
        float v = bf2f((short)(x[i] & 0xFFFFu));
        float a = fabsf(v);
        if (a > 1e-5f && a < 1e5f) sane++;
    }
    atomicAdd(&cnt, sane);
    __syncthreads();
    if (threadIdx.x == 0) *flag = (cnt < 512) ? 1 : 0;
}

// Canonicalize to bf16: convert (fp32 source) or copy (bf16 source). n % 8 == 0.
__global__ void to_bf16(const void* __restrict__ src, short* __restrict__ dst,
                        int n, const int* __restrict__ flag) {
    const int i = (blockIdx.x * blockDim.x + threadIdx.x) * 8;
    if (i >= n) return;
    if (*flag) {
        const float* s = (const float*)src;
        short8 o;
#pragma unroll
        for (int j = 0; j < 8; j++) o[j] = f2bf(s[i + j]);
        *(short8*)&dst[i] = o;
    } else {
        *(short8*)&dst[i] = *(const short8*)((const short*)src + i);
    }
}

// C = A @ B^T (+bias), A[M,K], B[N,K] row-major bf16.
// DUAL: output dtype chosen at runtime by *flag (fp32 vs bf16); else bf16.
template <bool DUAL>
__global__ __launch_bounds__(256) void gemm_bt(
    const short* __restrict__ A, const short* __restrict__ Bm,
    const short* __restrict__ bias_bf, void* __restrict__ Cout,
    int M, int N, int K, const int* __restrict__ flag)
{
    __shared__ short As[128 * 32];
    __shared__ short Bs[128 * 32];
    const int tid  = threadIdx.x;
    const int lane = tid & 63;
    const int wave = tid >> 6;
    const int quad = lane >> 4;
    const int lcol = lane & 15;
    const int m0 = blockIdx.y * 128;
    const int n0 = blockIdx.x * 128;
    const int wm = (wave >> 1) * 64;
    const int wn = (wave & 1) * 64;
    const int isf32 = DUAL ? *flag : 0;

    f32x4 acc[4][4];
#pragma unroll
    for (int i = 0; i < 4; i++)
#pragma unroll
        for (int j = 0; j < 4; j++) acc[i][j] = f32x4{0.f, 0.f, 0.f, 0.f};

    const int idx0 = tid * 8;            // element index in 128x32 tile
    const int row0 = idx0 >> 5, col0 = idx0 & 31;
    const int idx1 = (256 + tid) * 8;
    const int row1 = idx1 >> 5, col1 = idx1 & 31;

    for (int k0 = 0; k0 < K; k0 += 32) {
        async16(&A[(size_t)(m0 + row0) * K + k0 + col0], &As[idx0]);
        async16(&A[(size_t)(m0 + row1) * K + k0 + col1], &As[idx1]);
        async16(&Bm[(size_t)(n0 + row0) * K + k0 + col0], &Bs[idx0]);
        async16(&Bm[(size_t)(n0 + row1) * K + k0 + col1], &Bs[idx1]);
        __syncthreads();

        short8 af[4], bfr[4];
#pragma unroll
        for (int mi = 0; mi < 4; mi++)
            af[mi] = *(const short8*)&As[(wm + mi * 16 + lcol) * 32 + quad * 8];
#pragma unroll
        for (int ni = 0; ni < 4; ni++)
            bfr[ni] = *(const short8*)&Bs[(wn + ni * 16 + lcol) * 32 + quad * 8];
#pragma unroll
        for (int mi = 0; mi < 4; mi++)
#pragma unroll
            for (int ni = 0; ni < 4; ni++)
                acc[mi][ni] = __builtin_amdgcn_mfma_f32_16x16x32_bf16(
                    af[mi], bfr[ni], acc[mi][ni], 0, 0, 0);
        __syncthreads();
    }

#pragma unroll
    for (int ni = 0; ni < 4; ni++) {
        const int col = n0 + wn + ni * 16 + lcol;
        const float bv = bias_bf ? bf2f(bias_bf[col]) : 0.f;
#pragma unroll
        for (int mi = 0; mi < 4; mi++) {
            const int row = m0 + wm + mi * 16 + quad * 4;
#pragma unroll
            for (int r = 0; r < 4; r++) {
                const float val = acc[mi][ni][r] + bv;
                const size_t off = (size_t)(row + r) * N + col;
                if (DUAL && isf32) ((float*)Cout)[off] = val;
                else               ((short*)Cout)[off] = f2bf(val);
            }
        }
    }
}

// Flash attention v2: one block = 64 Q rows of one (b,h); 4 waves x 16 Q rows.
// 64-key tiles, conflict-free LDS banking, register prefetch pipeline.
// qkv layout per reference: col = h*192 + {0:q, 64:k, 128:v} + d.
__global__ __launch_bounds__(256) void attn(const short* __restrict__ qkv,
                                            short* __restrict__ att)
{
    __shared__ short lds_k[64][72];      // K  [key][d], pad 64->72 (stride 36 dw)
    __shared__ short lds_vt[64][68];     // V^T [d][key], pad 64->68 (stride 34 dw)
    __shared__ short lds_p[4][16][76];   // per-wave P [q][key], pad 64->76 (stride 38 dw)

    const int tid  = threadIdx.x;
    const int lane = tid & 63;
    const int wave = tid >> 6;
    const int quad = lane >> 4;
    const int lcol = lane & 15;

    const int qblk = blockIdx.x & 31;    // T/64 = 32
    const int bh   = blockIdx.x >> 5;
    const int b    = bh >> 4;            // H = 16
    const int h    = bh & 15;
    const int q0   = qblk * 64;
    const int qw0  = q0 + wave * 16;

    const size_t rowstride = 3 * C_;     // 3072
    const size_t bhbase = (size_t)b * T_ * rowstride + (size_t)h * (3 * HD_);

    // Q fragments (A-operand: m=lcol, k=quad*8+j, two d-halves)
    short8 qf0, qf1;
    {
        const size_t base = bhbase + (size_t)(qw0 + lcol) * rowstride + quad * 8;
        qf0 = *(const short8*)&qkv[base];
        qf1 = *(const short8*)&qkv[base + 32];
    }

    const float NEG = -1e30f;            // finite sentinel
    f32x4 o[4];
#pragma unroll
    for (int i = 0; i < 4; i++) o[i] = f32x4{0.f, 0.f, 0.f, 0.f};
    float m_i[4], l_i[4];
#pragma unroll
    for (int r = 0; r < 4; r++) { m_i[r] = NEG; l_i[r] = 0.f; }

    // staging assignments:
    // K: 4 lanes per key-row, contiguous 32B each -> vectorized b128 LDS writes
    const int kkey = tid >> 2;           // 0..63
    const int kdp  = (tid & 3) * 16;     // 0,16,32,48
    // V: one key per lane (wave spans all 64 keys at fixed d-chunk) ->
    //    scatter banks = 34*d + key/2 : all 32 banks, 2 lanes each (free)
    const int vkey = tid & 63;
    const int vd0  = (tid >> 6) * 16;    // 0,16,32,48

    short8 kA, kB, vA, vB;
    auto load_tile = [&](int k0) {
        const size_t kb = bhbase + (size_t)(k0 + kkey) * rowstride + HD_ + kdp;
        kA = *(const short8*)&qkv[kb];
        kB = *(const short8*)&qkv[kb + 8];
        const size_t vb = bhbase + (size_t)(k0 + vkey) * rowstride + 2 * HD_ + vd0;
        vA = *(const short8*)&qkv[vb];
        vB = *(const short8*)&qkv[vb + 8];
    };

    load_tile(0);

    const int ntiles = qblk + 1;
    for (int kt = 0; kt < ntiles; ++kt) {
        if (kt) __syncthreads();         // previous tile's LDS reads done
        *(short8*)&lds_k[kkey][kdp]     = kA;
        *(short8*)&lds_k[kkey][kdp + 8] = kB;
#pragma unroll
        for (int j = 0; j < 8; j++) {
            lds_vt[vd0 + j][vkey]     = vA[j];
            lds_vt[vd0 + 8 + j][vkey] = vB[j];
        }
        __syncthreads();
        if (kt + 1 < ntiles) load_tile((kt + 1) * 64);  // prefetch overlaps compute

        const int k0 = kt * 64;
        const bool last = (kt == qblk);

        // S[t] covers keys k0 + t*16 + lcol
        f32x4 S[4];
#pragma unroll
        for (int t = 0; t < 4; t++) {
            const short8 kf0 = *(const short8*)&lds_k[t * 16 + lcol][quad * 8];
            const short8 kf1 = *(const short8*)&lds_k[t * 16 + lcol][32 + quad * 8];
            S[t] = f32x4{0.f, 0.f, 0.f, 0.f};
            S[t] = __builtin_amdgcn_mfma_f32_16x16x32_bf16(qf0, kf0, S[t], 0, 0, 0);
            S[t] = __builtin_amdgcn_mfma_f32_16x16x32_bf16(qf1, kf1, S[t], 0, 0, 0);
        }

        // online softmax per owned row (row quad*4+r, key cols t*16+lcol)
#pragma unroll
        for (int r = 0; r < 4; r++) {
            const int qrow = qw0 + quad * 4 + r;
            float s[4];
#pragma unroll
            for (int t = 0; t < 4; t++) {
                s[t] = S[t][r] * 0.125f;
                if (last && (k0 + t * 16 + lcol > qrow)) s[t] = NEG;
            }
            float mx = fmaxf(fmaxf(s[0], s[1]), fmaxf(s[2], s[3]));
#pragma unroll
            for (int off = 1; off < 16; off <<= 1) mx = fmaxf(mx, __shfl_xor(mx, off));
            const float mnew  = fmaxf(m_i[r], mx);
            const float alpha = __expf(m_i[r] - mnew);
            float p[4];
            float rs = 0.f;
#pragma unroll
            for (int t = 0; t < 4; t++) { p[t] = __expf(s[t] - mnew); rs += p[t]; }
#pragma unroll
            for (int off = 1; off < 16; off <<= 1) rs += __shfl_xor(rs, off);
            l_i[r] = l_i[r] * alpha + rs;
            m_i[r] = mnew;
#pragma unroll
            for (int dt = 0; dt < 4; dt++) o[dt][r] *= alpha;
#pragma unroll
            for (int t = 0; t < 4; t++)
                lds_p[wave][quad * 4 + r][t * 16 + lcol] = f2bf(p[t]);
        }

        // O += P V  (P: A-operand from per-wave LDS; V^T: B-operand)
        const short8 pf0 = *(const short8*)&lds_p[wave][lcol][quad * 8];
        const short8 pf1 = *(const short8*)&lds_p[wave][lcol][32 + quad * 8];
#pragma unroll
        for (int dt = 0; dt < 4; dt++) {
            const short8 vf0 = *(const short8*)&lds_vt[dt * 16 + lcol][quad * 8];
            const short8 vf1 = *(const short8*)&lds_vt[dt * 16 + lcol][32 + quad * 8];
            o[dt] = __builtin_amdgcn_mfma_f32_16x16x32_bf16(pf0, vf0, o[dt], 0, 0, 0);
            o[dt] = __builtin_amdgcn_mfma_f32_16x16x32_bf16(pf1, vf1, o[dt], 0, 0, 0);
        }
    }

    // normalize + store: att[b, q, h*64 + d]
#pragma unroll
    for (int r = 0; r < 4; r++) {
        const float inv = (l_i[r] > 0.f) ? 1.f / l_i[r] : 0.f;
        const int qrow = qw0 + quad * 4 + r;
#pragma unroll
        for (int dt = 0; dt < 4; dt++) {
            const int col = h * HD_ + dt * 16 + lcol;
            att[(size_t)(b * T_ + qrow) * C_ + col] = f2bf(o[dt][r] * inv);
        }
    }
}

extern "C" void kernel_launch(void* const* d_in, const int* in_sizes, int n_in,
                              void* d_out, int out_size, void* d_ws, size_t ws_size,
                              hipStream_t stream) {
    const int n_x  = B_ * T_ * C_;        // 8388608
    const int n_wq = 3 * C_ * C_;         // 3145728
    const int n_wp = C_ * C_;             // 1048576

    char* ws = (char*)d_ws;
    short* qkv     = (short*)(ws);                               // 50331648 B
    short* x_or_at = (short*)(ws + 50331648);                    // 16777216 B (x_bf, then att)
    short* wq_bf   = (short*)(ws + 50331648 + 16777216);         //  6291456 B
    short* wp_bf   = (short*)(ws + 50331648 + 16777216 + 6291456);           // 2097152 B
    short* bias_bf = (short*)(ws + 50331648 + 16777216 + 6291456 + 2097152); //    2048 B
    int*   flag    = (int*)  (ws + 50331648 + 16777216 + 6291456 + 2097152 + 2048);

    dim3 blk(256);

    detect_f32<<<1, blk, 0, stream>>>((const uint32_t*)d_in[0], flag);

    to_bf16<<<dim3((n_x  / 8 + 255) / 256), blk, 0, stream>>>(d_in[0], x_or_at, n_x,  flag);
    to_bf16<<<dim3((n_wq / 8 + 255) / 256), blk, 0, stream>>>(d_in[1], wq_bf,   n_wq, flag);
    to_bf16<<<dim3((n_wp / 8 + 255) / 256), blk, 0, stream>>>(d_in[2], wp_bf,   n_wp, flag);
    to_bf16<<<dim3(1), blk, 0, stream>>>(d_in[3], bias_bf, C_, flag);

    // qkv = x @ W_qkv^T   [8192,3072]
    gemm_bt<false><<<dim3((3 * C_) / 128, (B_ * T_) / 128), blk, 0, stream>>>(
        x_or_at, wq_bf, nullptr, qkv, B_ * T_, 3 * C_, C_, flag);

    // attention -> att (reuses x_bf region; x no longer needed)
    attn<<<dim3(B_ * H_ * (T_ / 64)), blk, 0, stream>>>(qkv, x_or_at);

    // out = att @ W_proj^T + b_proj  (output dtype per flag)
    gemm_bt<true><<<dim3(C_ / 128, (B_ * T_) / 128), blk, 0, stream>>>(
        x_or_at, wp_bf, bias_bf, d_out, B_ * T_, C_, C_, flag);
}